// Round 5
// baseline (216.267 us; speedup 1.0000x reference)
//
#include <hip/hip_runtime.h>

// B=8, C=256, H=W=32 -> S=1024; NH=8, DK=256; qkv dim 6144.
#define NH    8
#define DK    256
#define SS    1024
// q is pre-scaled by SCALE*log2(e) in k1 so softmax runs in exp2 domain.
#define QSCALE 0.09016844136947155f   // (1/16) * 1.4426950408889634
#define TSH   8192                    // shorts per 16 KB tile (32 rows x 256)

using frag8  = __attribute__((ext_vector_type(8))) short;   // 8 bf16 (4 VGPRs)
using f32x4  = __attribute__((ext_vector_type(4))) float;   // 16x16 MFMA acc
using f32x16 = __attribute__((ext_vector_type(16))) float;  // 32x32 MFMA acc

__device__ __forceinline__ unsigned short f2bf(float f) {
    unsigned int u = __float_as_uint(f);
    return (unsigned short)((u + 0x7FFFu + ((u >> 16) & 1u)) >> 16);   // RNE
}
// pack two floats -> two bf16 in one uint (lo, hi), RNE
__device__ __forceinline__ unsigned int pk2bf(float lo, float hi) {
    unsigned int ul = __float_as_uint(lo), uh = __float_as_uint(hi);
    ul += 0x7FFFu + ((ul >> 16) & 1u);
    uh += 0x7FFFu + ((uh >> 16) & 1u);
    return (ul >> 16) | (uh & 0xFFFF0000u);
}

// async global->LDS, 16B per lane; LDS dest = wave-uniform base + lane*16.
__device__ __forceinline__ void load_lds16(const void* g, void* l) {
    __builtin_amdgcn_global_load_lds(
        (const __attribute__((address_space(1))) unsigned int*)g,
        (__attribute__((address_space(3))) unsigned int*)l, 16, 0, 0);
}

// Tiled layouts (shorts); k2 staging is a contiguous 16 KB copy per tile.
//  q/k: (bh*32 + s/32)*TSH + (d/8)*256 + (s%32)*8 + d%8
//  v  : key rows PERMUTED to match score-register order of lane (l32,hw):
//       chunk (g*2+hw) position j holds key = 16g + 4hw + (j&3) + 8*(j>>2)

// ---------------------------------------------------------------------------
// K0: all three transposes (x, Wp, Wo) fp32->bf16 in ONE launch. (r8 verbatim)
// ---------------------------------------------------------------------------
__global__ __launch_bounds__(256) void k0_all(
    const float* __restrict__ x,  unsigned short* __restrict__ xb,
    const float* __restrict__ Wp, unsigned short* __restrict__ Wpt,
    const float* __restrict__ Wo, unsigned short* __restrict__ Wot)
{
    __shared__ float tile[32][33];
    const int bid = blockIdx.x;
    const float* in; unsigned short* out; int R, C, c0, r0;
    if (bid < 2048) {            // x: [8][256][1024] -> [8][1024][256]
        int rr = bid;
        in = x + (size_t)(rr >> 8) * 256 * 1024;
        out = xb + (size_t)(rr >> 8) * 256 * 1024;
        R = 256; C = 1024; c0 = (rr & 31) * 32; r0 = ((rr >> 5) & 7) * 32;
    } else if (bid < 3584) {     // Wp: [256][6144] -> [6144][256]
        int rr = bid - 2048;
        in = Wp; out = Wpt; R = 256; C = 6144;
        c0 = (rr % 192) * 32; r0 = (rr / 192) * 32;
    } else {                     // Wo: [2048][256] -> [256][2048]
        int rr = bid - 3584;
        in = Wo; out = Wot; R = 2048; C = 256;
        c0 = (rr & 7) * 32; r0 = (rr >> 3) * 32;
    }
    const int tx = threadIdx.x & 31, ty = threadIdx.x >> 5;
#pragma unroll
    for (int j = 0; j < 4; j++)
        tile[ty + j * 8][tx] = in[(size_t)(r0 + ty + j * 8) * C + c0 + tx];
    __syncthreads();
#pragma unroll
    for (int j = 0; j < 4; j++)
        out[(size_t)(c0 + ty + j * 8) * R + r0 + tx] = f2bf(tile[tx][ty + j * 8]);
}

// ---------------------------------------------------------------------------
// K1: qkv = xt @ Wp + bp, bf16 MFMA. 256x128 tile, 8 waves, BK=32 dbuf.
// (r3 version — kept.)
// ---------------------------------------------------------------------------
__global__ __launch_bounds__(512) void k1_qkv(
    const unsigned short* __restrict__ xb, const unsigned short* __restrict__ Wpt,
    const float* __restrict__ bp,
    unsigned short* __restrict__ qb, unsigned short* __restrict__ kb,
    unsigned short* __restrict__ vb)
{
    __shared__ unsigned short As[2][256 * 32];   // xb tile (256 tokens x 32 k)
    __shared__ unsigned short Bs[2][128 * 32];   // Wpt tile (128 qkv dims x 32 k)
    const int t = threadIdx.x;
    const int wave = t >> 6, lane = t & 63;
    const int quad = lane >> 4, l16 = lane & 15;
    const int n0 = blockIdx.x * 128, m0 = blockIdx.y * 256;
    const int b = m0 >> 10, s0 = m0 & 1023;
    const int lr = lane >> 2, lc = (lane & 3) * 8;

    const int h = n0 / 768;
    const int rem = n0 - h * 768;
    const int tt = rem >> 8;                    // 0=q 1=k 2=v (block-uniform)

    // Fragment-row offsets: Fa has 128 rows (dims) for q/k, 256 (tokens) for v.
    const int aoff = (tt < 2) ? (wave & 1) * 64 : (wave >> 1) * 64;
    const int boff = (tt < 2) ? (wave >> 1) * 64 : (wave & 1) * 64;

    const unsigned short* Ag = xb + (size_t)(b * 1024 + s0) * 256;
    const unsigned short* Bg = Wpt + (size_t)n0 * 256;

    f32x4 acc[4][4];
#pragma unroll
    for (int i = 0; i < 4; i++)
#pragma unroll
        for (int j = 0; j < 4; j++) acc[i][j] = (f32x4){0.f, 0.f, 0.f, 0.f};

    auto stage = [&](int buf, int kt) {
        const int k0 = kt * 32;
#pragma unroll
        for (int j = 0; j < 2; j++) {           // A: 16 chunks of 16 rows
            int ch = wave + j * 8;
            load_lds16(Ag + (size_t)(ch * 16 + lr) * 256 + k0 + lc, &As[buf][ch * 512]);
        }
        load_lds16(Bg + (size_t)(wave * 16 + lr) * 256 + k0 + lc, &Bs[buf][wave * 512]);
    };

    stage(0, 0);
    __syncthreads();

    for (int kt = 0; kt < 8; kt++) {
        const int cur = kt & 1;
        if (kt < 7) stage(cur ^ 1, kt + 1);
        const unsigned short* Fa = (tt < 2) ? &Bs[cur][0] : &As[cur][0];
        const unsigned short* Fb = (tt < 2) ? &As[cur][0] : &Bs[cur][0];
        frag8 af[4], bf[4];
#pragma unroll
        for (int i = 0; i < 4; i++)
            af[i] = *(const frag8*)(&Fa[(aoff + i * 16 + l16) * 32 + quad * 8]);
#pragma unroll
        for (int j = 0; j < 4; j++)
            bf[j] = *(const frag8*)(&Fb[(boff + j * 16 + l16) * 32 + quad * 8]);
#pragma unroll
        for (int i = 0; i < 4; i++)
#pragma unroll
            for (int j = 0; j < 4; j++)
                acc[i][j] = __builtin_amdgcn_mfma_f32_16x16x32_bf16(af[i], bf[j], acc[i][j], 0, 0, 0);
        __syncthreads();
    }

    const int dcol0 = rem & 255;
    const size_t bh = (size_t)(b * NH + h);

    if (tt < 2) {
        // acc rows (i over aoff) = qkv dims; cols (j over boff) = tokens.
        const float sc = (tt == 0) ? QSCALE : 1.0f;
        unsigned short* dst = (tt == 0 ? qb : kb) + bh * 32 * TSH;
#pragma unroll
        for (int i = 0; i < 4; i++) {
            const int mloc = aoff + i * 16;
            float4 b4 = *(const float4*)(&bp[n0 + mloc + quad * 4]);
            const int octet = ((dcol0 + mloc) >> 3) + (quad >> 1);
            const int drem4 = (quad & 1) * 4;
#pragma unroll
            for (int j = 0; j < 4; j++) {
                const int s = s0 + boff + j * 16 + l16;
                unsigned short* cell = dst + (size_t)(s >> 5) * TSH
                                     + octet * 256 + (s & 31) * 8 + drem4;
                uint2 st;
                st.x = pk2bf((acc[i][j][0] + b4.x) * sc, (acc[i][j][1] + b4.y) * sc);
                st.y = pk2bf((acc[i][j][2] + b4.z) * sc, (acc[i][j][3] + b4.w) * sc);
                *(uint2*)cell = st;
            }
        }
    } else {
        // acc rows (i over aoff) = tokens; cols (j over boff) = dims.
        unsigned short* dst = vb + bh * 32 * TSH;
        const int chunk = (quad & 1) * 2048;
        const int jjb = (quad & 2) * 2;
        float bias[4];
#pragma unroll
        for (int j = 0; j < 4; j++) bias[j] = bp[n0 + boff + j * 16 + l16];
#pragma unroll
        for (int j = 0; j < 4; j++) {
            int d = dcol0 + boff + j * 16 + l16;
#pragma unroll
            for (int i = 0; i < 4; i++) {
                int g = ((aoff >> 4) + i) & 1;   // aoff>>4 even -> g = i&1
                size_t tile = (size_t)((s0 + aoff + i * 16) >> 5) * TSH;
                uint2 st;
                st.x = pk2bf(acc[i][j][0] + bias[j], acc[i][j][1] + bias[j]);
                st.y = pk2bf(acc[i][j][2] + bias[j], acc[i][j][3] + bias[j]);
                *(uint2*)(&dst[tile + g * 4096 + chunk + d * 8 + jjb]) = st;
            }
        }
    }
}

// ---------------------------------------------------------------------------
// K2: attention — r0-verbatim (best measured: 86.3us). K AND V double-
// buffered in LDS via global_load_lds, plain __syncthreads, NO setprio.
// Cross-round ledger: r0=86.3; +setprio-V-LDS=115; +setprio+vmcnt=92-97;
// deferred-PV+3buf=88.4. The compiler's own schedule at 2 blocks/CU wins.
// ---------------------------------------------------------------------------
__global__ __launch_bounds__(256, 2) void k2_attn(
    const unsigned short* __restrict__ qb, const unsigned short* __restrict__ kb,
    const unsigned short* __restrict__ vb, unsigned short* __restrict__ ob)
{
    __shared__ unsigned short Ks[2][TSH];
    __shared__ unsigned short Vs[2][TSH];

    const int t = threadIdx.x;
    const int wave = t >> 6, lane = t & 63;
    const int l32 = lane & 31, hw = lane >> 5;

    const int flat = blockIdx.x;
    const int xcd = flat & 7, tt2 = flat >> 3;
    const int qt = tt2 & 7;
    const int bh = xcd * 8 + (tt2 >> 3);

    const int qrow0 = qt * 128 + wave * 32;

    frag8 qf[16];
    {
        const unsigned short* qp = qb + ((size_t)bh * 32 + qt * 4 + wave) * TSH
                                 + hw * 256 + l32 * 8;
#pragma unroll
        for (int s = 0; s < 16; s++) qf[s] = *(const frag8*)(qp + s * 512);
    }

    f32x16 acc[8];
#pragma unroll
    for (int nb = 0; nb < 8; nb++)
#pragma unroll
        for (int r = 0; r < 16; r++) acc[nb][r] = 0.f;
    float lsum = 0.f;

    const unsigned short* kstg = kb + (size_t)bh * 32 * TSH + wave * 2048 + lane * 8;
    const unsigned short* vstg = vb + (size_t)bh * 32 * TSH + wave * 2048 + lane * 8;

    auto prefetch = [&](int buf, int kt) {
#pragma unroll
        for (int j = 0; j < 4; j++) {
            load_lds16(kstg + (size_t)kt * TSH + j * 512, &Ks[buf][wave * 2048 + j * 512]);
            load_lds16(vstg + (size_t)kt * TSH + j * 512, &Vs[buf][wave * 2048 + j * 512]);
        }
    };

    auto body = [&](const unsigned short* Kb, const unsigned short* Vb) {
        f32x16 sa0, sa1;
#pragma unroll
        for (int r = 0; r < 16; r++) { sa0[r] = 0.f; sa1[r] = 0.f; }
#pragma unroll
        for (int s = 0; s < 16; s += 2) {
            frag8 kf0 = *(const frag8*)(Kb + (2 * s + hw) * 256 + l32 * 8);
            frag8 kf1 = *(const frag8*)(Kb + (2 * s + 2 + hw) * 256 + l32 * 8);
            sa0 = __builtin_amdgcn_mfma_f32_32x32x16_bf16(kf0, qf[s], sa0, 0, 0, 0);
            sa1 = __builtin_amdgcn_mfma_f32_32x32x16_bf16(kf1, qf[s + 1], sa1, 0, 0, 0);
        }
        float p[16];
#pragma unroll
        for (int e = 0; e < 16; e++) {
            p[e] = exp2f(sa0[e] + sa1[e]);
            lsum += p[e];
        }
        frag8 pf[2];
#pragma unroll
        for (int g = 0; g < 2; g++) {
            uint4 w;
            w.x = pk2bf(p[g * 8 + 0], p[g * 8 + 1]);
            w.y = pk2bf(p[g * 8 + 2], p[g * 8 + 3]);
            w.z = pk2bf(p[g * 8 + 4], p[g * 8 + 5]);
            w.w = pk2bf(p[g * 8 + 6], p[g * 8 + 7]);
            pf[g] = *(frag8*)&w;
        }
        // PV: A=pf, B=vf -> D[m=qrow][col=dcol] (r8 orientation)
#pragma unroll
        for (int g = 0; g < 2; g++)
#pragma unroll
            for (int nb = 0; nb < 8; nb++) {
                frag8 vf = *(const frag8*)(Vb + (g * 2 + hw) * 2048 + (nb * 32 + l32) * 8);
                acc[nb] = __builtin_amdgcn_mfma_f32_32x32x16_bf16(pf[g], vf, acc[nb], 0, 0, 0);
            }
    };

    prefetch(0, 0);
    __syncthreads();
    for (int kt = 0; kt < 30; kt += 2) {
        prefetch(1, kt + 1);
        body(&Ks[0][0], &Vs[0][0]);
        __syncthreads();
        prefetch(0, kt + 2);
        body(&Ks[1][0], &Vs[1][0]);
        __syncthreads();
    }
    prefetch(1, 31);
    body(&Ks[0][0], &Vs[0][0]);
    __syncthreads();
    body(&Ks[1][0], &Vs[1][0]);

    lsum += __shfl_xor(lsum, 32);
    const float linv = 1.f / lsum;        // lane (l32,hw) holds row l32's inverse

    unsigned short* og = ob + ((size_t)bh * SS + qrow0) * DK + l32;
#pragma unroll
    for (int r = 0; r < 16; r++) {
        const int rowl = (r & 3) + 8 * (r >> 2) + 4 * hw;
        const float li = __shfl(linv, rowl, 64);
        unsigned short* orow = og + (size_t)rowl * DK;
#pragma unroll
        for (int nb = 0; nb < 8; nb++)
            orow[nb * 32] = f2bf(acc[nb][r] * li);
    }
}

// ---------------------------------------------------------------------------
// K3: out = O @ Wo + bo + xt, bf16 MFMA, fp32 epilogue, [B,C,S].
// NEW: BK=128 (4 slices/step, was 2). Barriers halve (64->32), MFMA per
// barrier-pair doubles (8->16). Per-slice LDS layout and fragment reads are
// byte-identical to the BK=64 version (zero bank-conflict risk; counter=0).
// LDS 32->64 KB -> 2 blocks/CU = the grid-imposed residency (512/256), so
// no occupancy loss.
// ---------------------------------------------------------------------------
__global__ __launch_bounds__(256) void k3_proj(
    const unsigned short* __restrict__ ob, const unsigned short* __restrict__ Wot,
    const float* __restrict__ bo, const float* __restrict__ x,
    float* __restrict__ out)
{
    __shared__ unsigned short As[2][4][2048];
    __shared__ unsigned short Bs[2][4][2048];
    const int t = threadIdx.x;
    const int wave = t >> 6, lane = t & 63;
    const int quad = lane >> 4, l16 = lane & 15;
    const int n0 = blockIdx.x * 64, m0 = blockIdx.y * 64;
    const int b = m0 >> 10, s0 = m0 & 1023;
    const int mq = (wave >> 1) * 32, nq = (wave & 1) * 32;
    const int lr = lane >> 2, lc = (lane & 3) * 8;

    const unsigned short* Bg = Wot + (size_t)n0 * 2048;

    f32x4 acc[2][2];
#pragma unroll
    for (int i = 0; i < 2; i++)
#pragma unroll
        for (int j = 0; j < 2; j++) acc[i][j] = (f32x4){0.f, 0.f, 0.f, 0.f};

    auto stage = [&](int buf, int kt) {
        const int k0 = kt * 128;
        const int h = k0 >> 8, d0 = k0 & 255;        // 128 | 256 -> d0 in {0,128}
        const unsigned short* Ag = ob + (size_t)((b * 8 + h) * 1024 + s0) * 256 + d0;
#pragma unroll
        for (int sl = 0; sl < 4; sl++) {
            load_lds16(Ag + (size_t)(wave * 16 + lr) * 256 + sl * 32 + lc, &As[buf][sl][wave * 512]);
            load_lds16(Bg + (size_t)(wave * 16 + lr) * 2048 + k0 + sl * 32 + lc, &Bs[buf][sl][wave * 512]);
        }
    };

    stage(0, 0);
    __syncthreads();

    for (int kt = 0; kt < 16; kt++) {
        const int cur = kt & 1;
        if (kt < 15) stage(cur ^ 1, kt + 1);
#pragma unroll
        for (int sl = 0; sl < 4; sl++) {
            frag8 af[2], bf[2];
#pragma unroll
            for (int i = 0; i < 2; i++)
                af[i] = *(const frag8*)(&As[cur][sl][(mq + i * 16 + l16) * 32 + quad * 8]);
#pragma unroll
            for (int j = 0; j < 2; j++)
                bf[j] = *(const frag8*)(&Bs[cur][sl][(nq + j * 16 + l16) * 32 + quad * 8]);
#pragma unroll
            for (int i = 0; i < 2; i++)
#pragma unroll
                for (int j = 0; j < 2; j++)
                    acc[i][j] = __builtin_amdgcn_mfma_f32_16x16x32_bf16(af[i], bf[j], acc[i][j], 0, 0, 0);
        }
        __syncthreads();
    }

#pragma unroll
    for (int j = 0; j < 2; j++) {
        int c = n0 + nq + j * 16 + l16;
        float bias = bo[c];
#pragma unroll
        for (int i = 0; i < 2; i++) {
            int s = s0 + mq + i * 16 + quad * 4;
            size_t off = (size_t)(b * 256 + c) * 1024 + s;
            float4 xv = *(const float4*)(&x[off]);
            float4 ov;
            ov.x = acc[i][j][0] + bias + xv.x;
            ov.y = acc[i][j][1] + bias + xv.y;
            ov.z = acc[i][j][2] + bias + xv.z;
            ov.w = acc[i][j][3] + bias + xv.w;
            *(float4*)(&out[off]) = ov;
        }
    }
}

// ---------------------------------------------------------------------------
extern "C" void kernel_launch(void* const* d_in, const int* in_sizes, int n_in,
                              void* d_out, int out_size, void* d_ws, size_t ws_size,
                              hipStream_t stream)
{
    const float* x  = (const float*)d_in[0];
    const float* Wp = (const float*)d_in[1];
    const float* bp = (const float*)d_in[2];
    const float* Wo = (const float*)d_in[3];
    const float* bo = (const float*)d_in[4];
    float* out = (float*)d_out;

    char* ws = (char*)d_ws;
    unsigned short* qb  = (unsigned short*)(ws);                // tiled; O overwrites row-major
    unsigned short* kb  = (unsigned short*)(ws + 33554432);     // tiled
    unsigned short* vb  = (unsigned short*)(ws + 67108864);     // tiled, key-permuted
    unsigned short* xb  = (unsigned short*)(ws + 100663296);    // [B,S,C] bf16
    unsigned short* Wpt = (unsigned short*)(ws + 104857600);    // [6144,256] bf16
    unsigned short* Wot = (unsigned short*)(ws + 108003328);    // [256,2048] bf16

    k0_all<<<dim3(4096), 256, 0, stream>>>(x, xb, Wp, Wpt, Wo, Wot);
    k1_qkv<<<dim3(48, 32), 512, 0, stream>>>(xb, Wpt, bp, qb, kb, vb);
    k2_attn<<<dim3(512), 256, 0, stream>>>(qb, kb, vb, qb /* O over Q */);
    k3_proj<<<dim3(4, 128), 256, 0, stream>>>(qb, Wot, bo, x, out);
}

// Round 6
// 214.427 us; speedup vs baseline: 1.0086x; 1.0086x over previous
//
#include <hip/hip_runtime.h>

// B=8, C=256, H=W=32 -> S=1024; NH=8, DK=256; qkv dim 6144.
#define NH    8
#define DK    256
#define SS    1024
// q is pre-scaled by SCALE*log2(e) in k1 so softmax runs in exp2 domain.
#define QSCALE 0.09016844136947155f   // (1/16) * 1.4426950408889634
#define TSH   8192                    // shorts per 16 KB tile (32 rows x 256)

using frag8  = __attribute__((ext_vector_type(8))) short;   // 8 bf16 (4 VGPRs)
using f32x4  = __attribute__((ext_vector_type(4))) float;   // 16x16 MFMA acc
using f32x16 = __attribute__((ext_vector_type(16))) float;  // 32x32 MFMA acc

__device__ __forceinline__ unsigned short f2bf(float f) {
    unsigned int u = __float_as_uint(f);
    return (unsigned short)((u + 0x7FFFu + ((u >> 16) & 1u)) >> 16);   // RNE
}
// pack two floats -> two bf16 in one uint (lo, hi), RNE
__device__ __forceinline__ unsigned int pk2bf(float lo, float hi) {
    unsigned int ul = __float_as_uint(lo), uh = __float_as_uint(hi);
    ul += 0x7FFFu + ((ul >> 16) & 1u);
    uh += 0x7FFFu + ((uh >> 16) & 1u);
    return (ul >> 16) | (uh & 0xFFFF0000u);
}

// async global->LDS, 16B per lane; LDS dest = wave-uniform base + lane*16.
__device__ __forceinline__ void load_lds16(const void* g, void* l) {
    __builtin_amdgcn_global_load_lds(
        (const __attribute__((address_space(1))) unsigned int*)g,
        (__attribute__((address_space(3))) unsigned int*)l, 16, 0, 0);
}

// Tiled layouts (shorts); k2 staging is a contiguous 16 KB copy per tile.
//  q/k: (bh*32 + s/32)*TSH + (d/8)*256 + (s%32)*8 + d%8
//  v  : key rows PERMUTED to match score-register order of lane (l32,hw):
//       chunk (g*2+hw) position j holds key = 16g + 4hw + (j&3) + 8*(j>>2)

// ---------------------------------------------------------------------------
// K0: all three transposes (x, Wp, Wo) fp32->bf16 in ONE launch. (r8 verbatim)
// ---------------------------------------------------------------------------
__global__ __launch_bounds__(256) void k0_all(
    const float* __restrict__ x,  unsigned short* __restrict__ xb,
    const float* __restrict__ Wp, unsigned short* __restrict__ Wpt,
    const float* __restrict__ Wo, unsigned short* __restrict__ Wot)
{
    __shared__ float tile[32][33];
    const int bid = blockIdx.x;
    const float* in; unsigned short* out; int R, C, c0, r0;
    if (bid < 2048) {            // x: [8][256][1024] -> [8][1024][256]
        int rr = bid;
        in = x + (size_t)(rr >> 8) * 256 * 1024;
        out = xb + (size_t)(rr >> 8) * 256 * 1024;
        R = 256; C = 1024; c0 = (rr & 31) * 32; r0 = ((rr >> 5) & 7) * 32;
    } else if (bid < 3584) {     // Wp: [256][6144] -> [6144][256]
        int rr = bid - 2048;
        in = Wp; out = Wpt; R = 256; C = 6144;
        c0 = (rr % 192) * 32; r0 = (rr / 192) * 32;
    } else {                     // Wo: [2048][256] -> [256][2048]
        int rr = bid - 3584;
        in = Wo; out = Wot; R = 2048; C = 256;
        c0 = (rr & 7) * 32; r0 = (rr >> 3) * 32;
    }
    const int tx = threadIdx.x & 31, ty = threadIdx.x >> 5;
#pragma unroll
    for (int j = 0; j < 4; j++)
        tile[ty + j * 8][tx] = in[(size_t)(r0 + ty + j * 8) * C + c0 + tx];
    __syncthreads();
#pragma unroll
    for (int j = 0; j < 4; j++)
        out[(size_t)(c0 + ty + j * 8) * R + r0 + tx] = f2bf(tile[tx][ty + j * 8]);
}

// ---------------------------------------------------------------------------
// K1: qkv = xt @ Wp + bp, bf16 MFMA. 256x128 tile, 8 waves, BK=32 dbuf.
// (r3 version — kept.)
// ---------------------------------------------------------------------------
__global__ __launch_bounds__(512) void k1_qkv(
    const unsigned short* __restrict__ xb, const unsigned short* __restrict__ Wpt,
    const float* __restrict__ bp,
    unsigned short* __restrict__ qb, unsigned short* __restrict__ kb,
    unsigned short* __restrict__ vb)
{
    __shared__ unsigned short As[2][256 * 32];   // xb tile (256 tokens x 32 k)
    __shared__ unsigned short Bs[2][128 * 32];   // Wpt tile (128 qkv dims x 32 k)
    const int t = threadIdx.x;
    const int wave = t >> 6, lane = t & 63;
    const int quad = lane >> 4, l16 = lane & 15;
    const int n0 = blockIdx.x * 128, m0 = blockIdx.y * 256;
    const int b = m0 >> 10, s0 = m0 & 1023;
    const int lr = lane >> 2, lc = (lane & 3) * 8;

    const int h = n0 / 768;
    const int rem = n0 - h * 768;
    const int tt = rem >> 8;                    // 0=q 1=k 2=v (block-uniform)

    // Fragment-row offsets: Fa has 128 rows (dims) for q/k, 256 (tokens) for v.
    const int aoff = (tt < 2) ? (wave & 1) * 64 : (wave >> 1) * 64;
    const int boff = (tt < 2) ? (wave >> 1) * 64 : (wave & 1) * 64;

    const unsigned short* Ag = xb + (size_t)(b * 1024 + s0) * 256;
    const unsigned short* Bg = Wpt + (size_t)n0 * 256;

    f32x4 acc[4][4];
#pragma unroll
    for (int i = 0; i < 4; i++)
#pragma unroll
        for (int j = 0; j < 4; j++) acc[i][j] = (f32x4){0.f, 0.f, 0.f, 0.f};

    auto stage = [&](int buf, int kt) {
        const int k0 = kt * 32;
#pragma unroll
        for (int j = 0; j < 2; j++) {           // A: 16 chunks of 16 rows
            int ch = wave + j * 8;
            load_lds16(Ag + (size_t)(ch * 16 + lr) * 256 + k0 + lc, &As[buf][ch * 512]);
        }
        load_lds16(Bg + (size_t)(wave * 16 + lr) * 256 + k0 + lc, &Bs[buf][wave * 512]);
    };

    stage(0, 0);
    __syncthreads();

    for (int kt = 0; kt < 8; kt++) {
        const int cur = kt & 1;
        if (kt < 7) stage(cur ^ 1, kt + 1);
        const unsigned short* Fa = (tt < 2) ? &Bs[cur][0] : &As[cur][0];
        const unsigned short* Fb = (tt < 2) ? &As[cur][0] : &Bs[cur][0];
        frag8 af[4], bf[4];
#pragma unroll
        for (int i = 0; i < 4; i++)
            af[i] = *(const frag8*)(&Fa[(aoff + i * 16 + l16) * 32 + quad * 8]);
#pragma unroll
        for (int j = 0; j < 4; j++)
            bf[j] = *(const frag8*)(&Fb[(boff + j * 16 + l16) * 32 + quad * 8]);
#pragma unroll
        for (int i = 0; i < 4; i++)
#pragma unroll
            for (int j = 0; j < 4; j++)
                acc[i][j] = __builtin_amdgcn_mfma_f32_16x16x32_bf16(af[i], bf[j], acc[i][j], 0, 0, 0);
        __syncthreads();
    }

    const int dcol0 = rem & 255;
    const size_t bh = (size_t)(b * NH + h);

    if (tt < 2) {
        // acc rows (i over aoff) = qkv dims; cols (j over boff) = tokens.
        const float sc = (tt == 0) ? QSCALE : 1.0f;
        unsigned short* dst = (tt == 0 ? qb : kb) + bh * 32 * TSH;
#pragma unroll
        for (int i = 0; i < 4; i++) {
            const int mloc = aoff + i * 16;
            float4 b4 = *(const float4*)(&bp[n0 + mloc + quad * 4]);
            const int octet = ((dcol0 + mloc) >> 3) + (quad >> 1);
            const int drem4 = (quad & 1) * 4;
#pragma unroll
            for (int j = 0; j < 4; j++) {
                const int s = s0 + boff + j * 16 + l16;
                unsigned short* cell = dst + (size_t)(s >> 5) * TSH
                                     + octet * 256 + (s & 31) * 8 + drem4;
                uint2 st;
                st.x = pk2bf((acc[i][j][0] + b4.x) * sc, (acc[i][j][1] + b4.y) * sc);
                st.y = pk2bf((acc[i][j][2] + b4.z) * sc, (acc[i][j][3] + b4.w) * sc);
                *(uint2*)cell = st;
            }
        }
    } else {
        // acc rows (i over aoff) = tokens; cols (j over boff) = dims.
        unsigned short* dst = vb + bh * 32 * TSH;
        const int chunk = (quad & 1) * 2048;
        const int jjb = (quad & 2) * 2;
        float bias[4];
#pragma unroll
        for (int j = 0; j < 4; j++) bias[j] = bp[n0 + boff + j * 16 + l16];
#pragma unroll
        for (int j = 0; j < 4; j++) {
            int d = dcol0 + boff + j * 16 + l16;
#pragma unroll
            for (int i = 0; i < 4; i++) {
                int g = ((aoff >> 4) + i) & 1;   // aoff>>4 even -> g = i&1
                size_t tile = (size_t)((s0 + aoff + i * 16) >> 5) * TSH;
                uint2 st;
                st.x = pk2bf(acc[i][j][0] + bias[j], acc[i][j][1] + bias[j]);
                st.y = pk2bf(acc[i][j][2] + bias[j], acc[i][j][3] + bias[j]);
                *(uint2*)(&dst[tile + g * 4096 + chunk + d * 8 + jjb]) = st;
            }
        }
    }
}

// ---------------------------------------------------------------------------
// K2: attention — r0-verbatim (best measured: 85.4-86.3us across rounds).
// K AND V double-buffered in LDS via global_load_lds, plain __syncthreads,
// NO setprio. Ledger: r0=86.3; +setprio-V-direct=115; +setprio+vmcnt=92-97;
// deferred-PV+3buf=88.4; r5(this)=85.4-86.0. Compiler schedule at 2
// blocks/CU wins. 68.7 GF / 86us = ~800 TF = plain-HIP attn plateau.
// ---------------------------------------------------------------------------
__global__ __launch_bounds__(256, 2) void k2_attn(
    const unsigned short* __restrict__ qb, const unsigned short* __restrict__ kb,
    const unsigned short* __restrict__ vb, unsigned short* __restrict__ ob)
{
    __shared__ unsigned short Ks[2][TSH];
    __shared__ unsigned short Vs[2][TSH];

    const int t = threadIdx.x;
    const int wave = t >> 6, lane = t & 63;
    const int l32 = lane & 31, hw = lane >> 5;

    const int flat = blockIdx.x;
    const int xcd = flat & 7, tt2 = flat >> 3;
    const int qt = tt2 & 7;
    const int bh = xcd * 8 + (tt2 >> 3);

    const int qrow0 = qt * 128 + wave * 32;

    frag8 qf[16];
    {
        const unsigned short* qp = qb + ((size_t)bh * 32 + qt * 4 + wave) * TSH
                                 + hw * 256 + l32 * 8;
#pragma unroll
        for (int s = 0; s < 16; s++) qf[s] = *(const frag8*)(qp + s * 512);
    }

    f32x16 acc[8];
#pragma unroll
    for (int nb = 0; nb < 8; nb++)
#pragma unroll
        for (int r = 0; r < 16; r++) acc[nb][r] = 0.f;
    float lsum = 0.f;

    const unsigned short* kstg = kb + (size_t)bh * 32 * TSH + wave * 2048 + lane * 8;
    const unsigned short* vstg = vb + (size_t)bh * 32 * TSH + wave * 2048 + lane * 8;

    auto prefetch = [&](int buf, int kt) {
#pragma unroll
        for (int j = 0; j < 4; j++) {
            load_lds16(kstg + (size_t)kt * TSH + j * 512, &Ks[buf][wave * 2048 + j * 512]);
            load_lds16(vstg + (size_t)kt * TSH + j * 512, &Vs[buf][wave * 2048 + j * 512]);
        }
    };

    auto body = [&](const unsigned short* Kb, const unsigned short* Vb) {
        f32x16 sa0, sa1;
#pragma unroll
        for (int r = 0; r < 16; r++) { sa0[r] = 0.f; sa1[r] = 0.f; }
#pragma unroll
        for (int s = 0; s < 16; s += 2) {
            frag8 kf0 = *(const frag8*)(Kb + (2 * s + hw) * 256 + l32 * 8);
            frag8 kf1 = *(const frag8*)(Kb + (2 * s + 2 + hw) * 256 + l32 * 8);
            sa0 = __builtin_amdgcn_mfma_f32_32x32x16_bf16(kf0, qf[s], sa0, 0, 0, 0);
            sa1 = __builtin_amdgcn_mfma_f32_32x32x16_bf16(kf1, qf[s + 1], sa1, 0, 0, 0);
        }
        float p[16];
#pragma unroll
        for (int e = 0; e < 16; e++) {
            p[e] = exp2f(sa0[e] + sa1[e]);
            lsum += p[e];
        }
        frag8 pf[2];
#pragma unroll
        for (int g = 0; g < 2; g++) {
            uint4 w;
            w.x = pk2bf(p[g * 8 + 0], p[g * 8 + 1]);
            w.y = pk2bf(p[g * 8 + 2], p[g * 8 + 3]);
            w.z = pk2bf(p[g * 8 + 4], p[g * 8 + 5]);
            w.w = pk2bf(p[g * 8 + 6], p[g * 8 + 7]);
            pf[g] = *(frag8*)&w;
        }
        // PV: A=pf, B=vf -> D[m=qrow][col=dcol] (r8 orientation)
#pragma unroll
        for (int g = 0; g < 2; g++)
#pragma unroll
            for (int nb = 0; nb < 8; nb++) {
                frag8 vf = *(const frag8*)(Vb + (g * 2 + hw) * 2048 + (nb * 32 + l32) * 8);
                acc[nb] = __builtin_amdgcn_mfma_f32_32x32x16_bf16(pf[g], vf, acc[nb], 0, 0, 0);
            }
    };

    prefetch(0, 0);
    __syncthreads();
    for (int kt = 0; kt < 30; kt += 2) {
        prefetch(1, kt + 1);
        body(&Ks[0][0], &Vs[0][0]);
        __syncthreads();
        prefetch(0, kt + 2);
        body(&Ks[1][0], &Vs[1][0]);
        __syncthreads();
    }
    prefetch(1, 31);
    body(&Ks[0][0], &Vs[0][0]);
    __syncthreads();
    body(&Ks[1][0], &Vs[1][0]);

    lsum += __shfl_xor(lsum, 32);
    const float linv = 1.f / lsum;        // lane (l32,hw) holds row l32's inverse

    unsigned short* og = ob + ((size_t)bh * SS + qrow0) * DK + l32;
#pragma unroll
    for (int r = 0; r < 16; r++) {
        const int rowl = (r & 3) + 8 * (r >> 2) + 4 * hw;
        const float li = __shfl(linv, rowl, 64);
        unsigned short* orow = og + (size_t)rowl * DK;
#pragma unroll
        for (int nb = 0; nb < 8; nb++)
            orow[nb * 32] = f2bf(acc[nb][r] * li);
    }
}

// ---------------------------------------------------------------------------
// K3: out = O @ Wo + bo + xt, bf16 MFMA, fp32 epilogue, [B,C,S].
// REVERTED to BK=64 (r4 best): BK=128 measured ~+3us (r4->r5 isolation) —
// the doubled stage burst lengthens the per-step drain more than the halved
// barrier count saves.
// ---------------------------------------------------------------------------
__global__ __launch_bounds__(256) void k3_proj(
    const unsigned short* __restrict__ ob, const unsigned short* __restrict__ Wot,
    const float* __restrict__ bo, const float* __restrict__ x,
    float* __restrict__ out)
{
    __shared__ unsigned short As[2][2][2048];
    __shared__ unsigned short Bs[2][2][2048];
    const int t = threadIdx.x;
    const int wave = t >> 6, lane = t & 63;
    const int quad = lane >> 4, l16 = lane & 15;
    const int n0 = blockIdx.x * 64, m0 = blockIdx.y * 64;
    const int b = m0 >> 10, s0 = m0 & 1023;
    const int mq = (wave >> 1) * 32, nq = (wave & 1) * 32;
    const int lr = lane >> 2, lc = (lane & 3) * 8;

    const unsigned short* Bg = Wot + (size_t)n0 * 2048;

    f32x4 acc[2][2];
#pragma unroll
    for (int i = 0; i < 2; i++)
#pragma unroll
        for (int j = 0; j < 2; j++) acc[i][j] = (f32x4){0.f, 0.f, 0.f, 0.f};

    auto stage = [&](int buf, int kt) {
        const int k0 = kt * 64;
        const int h = k0 >> 8, d0 = k0 & 255;
        const unsigned short* Ag = ob + (size_t)((b * 8 + h) * 1024 + s0) * 256 + d0;
#pragma unroll
        for (int sl = 0; sl < 2; sl++) {
            load_lds16(Ag + (size_t)(wave * 16 + lr) * 256 + sl * 32 + lc, &As[buf][sl][wave * 512]);
            load_lds16(Bg + (size_t)(wave * 16 + lr) * 2048 + k0 + sl * 32 + lc, &Bs[buf][sl][wave * 512]);
        }
    };

    stage(0, 0);
    __syncthreads();

    for (int kt = 0; kt < 32; kt++) {
        const int cur = kt & 1;
        if (kt < 31) stage(cur ^ 1, kt + 1);
#pragma unroll
        for (int sl = 0; sl < 2; sl++) {
            frag8 af[2], bf[2];
#pragma unroll
            for (int i = 0; i < 2; i++)
                af[i] = *(const frag8*)(&As[cur][sl][(mq + i * 16 + l16) * 32 + quad * 8]);
#pragma unroll
            for (int j = 0; j < 2; j++)
                bf[j] = *(const frag8*)(&Bs[cur][sl][(nq + j * 16 + l16) * 32 + quad * 8]);
#pragma unroll
            for (int i = 0; i < 2; i++)
#pragma unroll
                for (int j = 0; j < 2; j++)
                    acc[i][j] = __builtin_amdgcn_mfma_f32_16x16x32_bf16(af[i], bf[j], acc[i][j], 0, 0, 0);
        }
        __syncthreads();
    }

#pragma unroll
    for (int j = 0; j < 2; j++) {
        int c = n0 + nq + j * 16 + l16;
        float bias = bo[c];
#pragma unroll
        for (int i = 0; i < 2; i++) {
            int s = s0 + mq + i * 16 + quad * 4;
            size_t off = (size_t)(b * 256 + c) * 1024 + s;
            float4 xv = *(const float4*)(&x[off]);
            float4 ov;
            ov.x = acc[i][j][0] + bias + xv.x;
            ov.y = acc[i][j][1] + bias + xv.y;
            ov.z = acc[i][j][2] + bias + xv.z;
            ov.w = acc[i][j][3] + bias + xv.w;
            *(float4*)(&out[off]) = ov;
        }
    }
}

// ---------------------------------------------------------------------------
extern "C" void kernel_launch(void* const* d_in, const int* in_sizes, int n_in,
                              void* d_out, int out_size, void* d_ws, size_t ws_size,
                              hipStream_t stream)
{
    const float* x  = (const float*)d_in[0];
    const float* Wp = (const float*)d_in[1];
    const float* bp = (const float*)d_in[2];
    const float* Wo = (const float*)d_in[3];
    const float* bo = (const float*)d_in[4];
    float* out = (float*)d_out;

    char* ws = (char*)d_ws;
    unsigned short* qb  = (unsigned short*)(ws);                // tiled; O overwrites row-major
    unsigned short* kb  = (unsigned short*)(ws + 33554432);     // tiled
    unsigned short* vb  = (unsigned short*)(ws + 67108864);     // tiled, key-permuted
    unsigned short* xb  = (unsigned short*)(ws + 100663296);    // [B,S,C] bf16
    unsigned short* Wpt = (unsigned short*)(ws + 104857600);    // [6144,256] bf16
    unsigned short* Wot = (unsigned short*)(ws + 108003328);    // [256,2048] bf16

    k0_all<<<dim3(4096), 256, 0, stream>>>(x, xb, Wp, Wpt, Wo, Wot);
    k1_qkv<<<dim3(48, 32), 512, 0, stream>>>(xb, Wpt, bp, qb, kb, vb);
    k2_attn<<<dim3(512), 256, 0, stream>>>(qb, kb, vb, qb /* O over Q */);
    k3_proj<<<dim3(4, 128), 256, 0, stream>>>(qb, Wot, bo, x, out);
}